// Round 13
// baseline (55.531 us; speedup 1.0000x reference)
//
#include <hip/hip_runtime.h>
#include <hip/hip_bf16.h>

// ---- problem constants ----
#define BATCH 16
#define CIN   12
#define HIMG  512
#define WIMG  512
#define OCH   768
#define KDIM  256            // 16*16 patch
#define HW    (HIMG*WIMG)    // 262144
#define NPATCH 1024          // 32*32 patches per batch

typedef __attribute__((ext_vector_type(8))) short short8;   // 8 bf16 = 4 VGPRs
typedef __attribute__((ext_vector_type(4))) float f32x4;

// ---------------------------------------------------------------------------
// Device bodies (shared by the phase kernels).
// mean: xm[b][h][w] = mean_c x[b][c][h][w], f32 -> bf16 (R1-validated body),
//       one half-batch (8 images) per call; idx local to the half.
// pack: w f32 -> bf16 in MFMA fragment-lane order (R2-validated):
//       packed[u], u = (ot*8+kk)*64+lane holds
//       w[ot*16+(lane&15)][kk*32+(lane>>4)*8 + j], j=0..7.
// gemm: LDS-free patch-embedding GEMM (R12-validated body), block =
//       (b, stripe-pair sp, o-quarter oq): 64 patches x 192 o-channels,
//       256 threads = 4 waves; wave owns 48 o (3 frags) x 64 m (4 frags).
// ---------------------------------------------------------------------------
__device__ __forceinline__ void mean_body(int local_bid, int tid, int hb,
                                          const float* __restrict__ x,
                                          __hip_bfloat16* __restrict__ xm) {
    int idx = local_bid * 256 + tid;                // float4 index within half
    int b = hb * 8 + (idx >> 16);                   // 65536 float4 per image
    int pos = (idx & 65535) << 2;
    const float* px = x + (size_t)b * CIN * HW + pos;
    float sx = 0.f, sy = 0.f, sz = 0.f, sw = 0.f;
    #pragma unroll
    for (int c = 0; c < CIN; ++c) {
        f32x4 v = *reinterpret_cast<const f32x4*>(px + (size_t)c * HW);
        sx += v.x; sy += v.y; sz += v.z; sw += v.w;
    }
    const float inv = 1.0f / 12.0f;
    union { ushort4 u4; __hip_bfloat16 h[4]; } o;
    o.h[0] = __float2bfloat16(sx * inv);
    o.h[1] = __float2bfloat16(sy * inv);
    o.h[2] = __float2bfloat16(sz * inv);
    o.h[3] = __float2bfloat16(sw * inv);
    *reinterpret_cast<ushort4*>(xm + (size_t)b * HW + pos) = o.u4;
}

__device__ __forceinline__ void pack_body(int u, const float* __restrict__ w,
                                          short8* __restrict__ wbp) {
    int lane = u & 63;
    int kk   = (u >> 6) & 7;
    int ot   = u >> 9;                               // 0..47
    int o = ot * 16 + (lane & 15);
    int k = kk * 32 + (lane >> 4) * 8;
    const float* src = w + (size_t)o * KDIM + k;
    f32x4 v0 = *reinterpret_cast<const f32x4*>(src);
    f32x4 v1 = *reinterpret_cast<const f32x4*>(src + 4);
    union { short8 s; __hip_bfloat16 h[8]; } t;
    t.h[0] = __float2bfloat16(v0.x);
    t.h[1] = __float2bfloat16(v0.y);
    t.h[2] = __float2bfloat16(v0.z);
    t.h[3] = __float2bfloat16(v0.w);
    t.h[4] = __float2bfloat16(v1.x);
    t.h[5] = __float2bfloat16(v1.y);
    t.h[6] = __float2bfloat16(v1.z);
    t.h[7] = __float2bfloat16(v1.w);
    wbp[u] = t.s;
}

__device__ __forceinline__ void gemm_body(int gid, int tid, int hb,
                                          const short8* __restrict__ wbp,
                                          const __hip_bfloat16* __restrict__ xm,
                                          const float* __restrict__ bias,
                                          float* __restrict__ out) {
    const int oq = gid & 3;                  // o-quarter (192 channels)
    const int sp = (gid >> 2) & 15;          // stripe pair (64 patches)
    const int b  = hb * 8 + (gid >> 6);

    const int lane = tid & 63;
    const int wv   = tid >> 6;               // 0..3
    const int lrow = lane & 15;
    const int lg   = lane >> 4;

    // B: direct per-lane 16 B loads from L2-resident xm (R12 layout)
    const __hip_bfloat16* xmb = xm + (size_t)b * HW + sp * (32 * WIMG)
                                + (lg >> 1) * WIMG + (lg & 1) * 8;
    int e0[4];
    #pragma unroll
    for (int fm = 0; fm < 4; ++fm) {
        const int ml = fm * 16 + lrow;
        e0[fm] = (ml >> 5) * (16 * WIMG) + (ml & 31) * 16;
    }

    f32x4 acc[3][4] = {};
    // weight 16-row tile base: (oq*192 + wv*48)/16 = oq*12 + wv*3
    const short8* wp = wbp + (size_t)(oq * 12 + wv * 3) * 8 * 64 + lane;

    #pragma unroll
    for (int kk = 0; kk < 8; ++kk) {
        short8 af[3], bf[4];
        #pragma unroll
        for (int fo = 0; fo < 3; ++fo)
            af[fo] = wp[(size_t)(fo * 8 + kk) * 64];
        #pragma unroll
        for (int fm = 0; fm < 4; ++fm)
            bf[fm] = *reinterpret_cast<const short8*>(xmb + e0[fm] + kk * (2 * WIMG));
        #pragma unroll
        for (int fo = 0; fo < 3; ++fo)
            #pragma unroll
            for (int fm = 0; fm < 4; ++fm)
                acc[fo][fm] = __builtin_amdgcn_mfma_f32_16x16x32_bf16(af[fo], bf[fm], acc[fo][fm], 0, 0, 0);
    }

    // epilogue: D row = o ((lane>>4)*4 + reg), col = m (lane&15)
    float* ob = out + (size_t)b * OCH * NPATCH + sp * 64;
    #pragma unroll
    for (int fo = 0; fo < 3; ++fo) {
        const int obase = oq * 192 + wv * 48 + fo * 16 + lg * 4;
        #pragma unroll
        for (int r = 0; r < 4; ++r) {
            const int o = obase + r;
            const float bv = bias[o];
            float* orow = ob + (size_t)o * NPATCH;
            #pragma unroll
            for (int fm = 0; fm < 4; ++fm)
                orow[fm * 16 + lrow] = acc[fo][fm][r] + bv;
        }
    }
}

// ---------------------------------------------------------------------------
// Phase kernels (software pipeline across launches):
//   K1: mean(b0..7) [2048 blocks] + pack [96 blocks]
//   K2: gemm(b0..7) [512 blocks, dispatched FIRST] + mean(b8..15) [2048]
//       -> gemm's writes/L2 streams overlap the second half's HBM reads.
//   K3: gemm(b8..15) [512 blocks]
// All dependencies are across-launch (stream-ordered) — no intra-kernel
// ordering assumptions, deterministic.
// ---------------------------------------------------------------------------
__global__ __launch_bounds__(256) void k1_kernel(
        const float* __restrict__ x, __hip_bfloat16* __restrict__ xm,
        const float* __restrict__ w, short8* __restrict__ wbp) {
    const int bid = blockIdx.x;
    if (bid < 2048) mean_body(bid, threadIdx.x, 0, x, xm);
    else            pack_body((bid - 2048) * 256 + threadIdx.x, w, wbp);
}

__global__ __launch_bounds__(256) void k2_kernel(
        const float* __restrict__ x, __hip_bfloat16* __restrict__ xm,
        const short8* __restrict__ wbp, const float* __restrict__ bias,
        float* __restrict__ out) {
    const int bid = blockIdx.x;
    if (bid < 512) gemm_body(bid, threadIdx.x, 0, wbp, xm, bias, out);
    else           mean_body(bid - 512, threadIdx.x, 1, x, xm);
}

__global__ __launch_bounds__(256) void k3_kernel(
        const short8* __restrict__ wbp, const __hip_bfloat16* __restrict__ xm,
        const float* __restrict__ bias, float* __restrict__ out) {
    gemm_body(blockIdx.x, threadIdx.x, 1, wbp, xm, bias, out);
}

// ---------------------------------------------------------------------------
extern "C" void kernel_launch(void* const* d_in, const int* in_sizes, int n_in,
                              void* d_out, int out_size, void* d_ws, size_t ws_size,
                              hipStream_t stream) {
    const float* x    = (const float*)d_in[0];
    const float* w    = (const float*)d_in[1];
    const float* bias = (const float*)d_in[2];
    float* out = (float*)d_out;

    __hip_bfloat16* xm = (__hip_bfloat16*)d_ws;                                   // 8 MiB
    short8* wbp = (short8*)((char*)d_ws + (size_t)BATCH * HW * 2);                // 384 KiB

    k1_kernel<<<2144, 256, 0, stream>>>(x, xm, w, wbp);
    k2_kernel<<<2560, 256, 0, stream>>>(x, xm, wbp, bias, out);
    k3_kernel<<<512,  256, 0, stream>>>(wbp, xm, bias, out);
}